// Round 5
// baseline (634.328 us; speedup 1.0000x reference)
//
#include <hip/hip_runtime.h>

static constexpr int NN = 50000;
static constexpr int NE = 1000000;

typedef short bf16x8 __attribute__((ext_vector_type(8)));
typedef float f32x4 __attribute__((ext_vector_type(4)));

__device__ inline float bf2f_raw(unsigned short u) {
    return __uint_as_float(((unsigned int)u) << 16);
}
__device__ inline unsigned short f2bf(float f) {
    unsigned int u = __float_as_uint(f);
    u += 0x7fffu + ((u >> 16) & 1u);
    return (unsigned short)(u >> 16);
}
__device__ inline void fmax2(float& a0, float& a1, unsigned int v) {
    a0 = fmaxf(a0, bf2f_raw((unsigned short)(v & 0xffffu)));
    a1 = fmaxf(a1, bf2f_raw((unsigned short)(v >> 16)));
}
__device__ inline unsigned int pack2(float f0, float f1) {
    return (unsigned int)f2bf(f0) | ((unsigned int)f2bf(f1) << 16);
}
// x_out pair = relu(a_pair + t), a packed bf16x2
__device__ inline unsigned int addrelu2(unsigned int a, float t0, float t1) {
    float f0 = fmaxf(bf2f_raw((unsigned short)(a & 0xffffu)) + t0, 0.f);
    float f1 = fmaxf(bf2f_raw((unsigned short)(a >> 16)) + t1, 0.f);
    return pack2(f0, f1);
}

// ---------------- CSR build ----------------

__global__ void hist_kernel(const int* __restrict__ dst, int* __restrict__ deg) {
    int e = blockIdx.x * blockDim.x + threadIdx.x;
    if (e < NE) atomicAdd(&deg[dst[e]], 1);
}

__global__ __launch_bounds__(1024) void scan_kernel(const int* __restrict__ deg,
                                                    int* __restrict__ rowstart) {
    __shared__ int wave_sums[16];
    __shared__ int carry_s;
    int tid = threadIdx.x;
    int lane = tid & 63;
    int wave = tid >> 6;
    if (tid == 0) carry_s = 0;
    __syncthreads();
    for (int base = 0; base < NN; base += 1024) {
        int idx = base + tid;
        int v = (idx < NN) ? deg[idx] : 0;
        int x = v;
        #pragma unroll
        for (int off = 1; off < 64; off <<= 1) {
            int y = __shfl_up(x, off);
            if (lane >= off) x += y;
        }
        if (lane == 63) wave_sums[wave] = x;
        __syncthreads();
        if (wave == 0 && lane < 16) {
            int s = wave_sums[lane];
            #pragma unroll
            for (int off = 1; off < 16; off <<= 1) {
                int y = __shfl_up(s, off);
                if (lane >= off) s += y;
            }
            wave_sums[lane] = s;
        }
        __syncthreads();
        int wave_off = wave ? wave_sums[wave - 1] : 0;
        int chunk_total = wave_sums[15];
        int carry = carry_s;
        if (idx < NN) rowstart[idx] = carry + wave_off + x - v;  // exclusive scan
        __syncthreads();
        if (tid == 0) carry_s = carry + chunk_total;
        __syncthreads();
    }
    if (tid == 0) rowstart[NN] = carry_s;
}

__global__ void scatter_kernel(const int* __restrict__ src, const int* __restrict__ dst,
                               const int* __restrict__ rowstart, int* __restrict__ cursor,
                               int* __restrict__ csr) {
    int e = blockIdx.x * blockDim.x + threadIdx.x;
    if (e < NE) {
        int d = dst[e];
        int pos = atomicAdd(&cursor[d], 1);
        csr[rowstart[d] + pos] = src[e];
    }
}

// ---------------- weight prep: bf16, transposed [COUT][CIN] ----------------

template<int CIN, int COUT>
__global__ void prep_split_t_kernel(const float* __restrict__ W,
                                    unsigned short* __restrict__ Wtbt,
                                    unsigned short* __restrict__ Wbt) {
    int t = blockIdx.x * blockDim.x + threadIdx.x;
    if (t >= CIN * COUT) return;
    int k = t / COUT, c = t % COUT;
    float wt = W[k * COUT + c];
    float wb = W[(CIN + k) * COUT + c];
    Wtbt[c * CIN + k] = f2bf(wt - wb);
    Wbt[c * CIN + k] = f2bf(wb);
}

template<int K, int N>
__global__ void prep_t_kernel(const float* __restrict__ W, unsigned short* __restrict__ Wt) {
    int t = blockIdx.x * blockDim.x + threadIdx.x;
    if (t >= K * N) return;
    int k = t / N, n = t % N;
    Wt[n * K + k] = f2bf(W[k * N + n]);
}

// ---------------- conv1 s = x @ Wb1 (K=3, elementwise) ----------------

__global__ void conv1_s_kernel(const float* __restrict__ x, const float* __restrict__ W1,
                               unsigned short* __restrict__ s) {
    int t = blockIdx.x * blockDim.x + threadIdx.x;
    int i = t >> 6, c = t & 63;
    if (i >= NN) return;
    float v = x[i * 3 + 0] * W1[3 * 64 + c] + x[i * 3 + 1] * W1[4 * 64 + c] +
              x[i * 3 + 2] * W1[5 * 64 + c];
    s[t] = f2bf(v);
}

// ---------------- conv1 fused edge-max + epilogue (C=64) ----------------
// one wave per node; lane-halves process alternate edges; a computed inline from x.

__global__ __launch_bounds__(256) void edge_fused_conv1_kernel(
    const unsigned short* __restrict__ s1, const int* __restrict__ rowstart,
    const int* __restrict__ csr, const float* __restrict__ x,
    const float* __restrict__ W1, const float* __restrict__ b1,
    unsigned short* __restrict__ x1) {
    int wid = (blockIdx.x * 256 + threadIdx.x) >> 6;
    int lane = threadIdx.x & 63;
    if (wid >= NN) return;
    int e0 = __builtin_amdgcn_readfirstlane(rowstart[wid]);
    int e1 = __builtin_amdgcn_readfirstlane(rowstart[wid + 1]);
    int h = lane >> 5, c0 = (lane & 31) * 2;
    float t0 = -INFINITY, t1 = -INFINITY;
    const unsigned short* sb = s1 + c0;
    int nedge = e1 - e0;
    for (int base = 0; base < nedge; base += 64) {
        int rem = nedge - base;
        int myj = csr[(lane < rem) ? (e0 + base + lane) : e0];
        int cnt = rem < 64 ? rem : 64;
        int cp = (cnt + 7) & ~7;
        for (int q = 0; q < cp; q += 8) {
            int j0 = __shfl(myj, q + 0 + h);
            int j1 = __shfl(myj, q + 2 + h);
            int j2 = __shfl(myj, q + 4 + h);
            int j3 = __shfl(myj, q + 6 + h);
            unsigned int v0 = *(const unsigned int*)(sb + (size_t)j0 * 64);
            unsigned int v1 = *(const unsigned int*)(sb + (size_t)j1 * 64);
            unsigned int v2 = *(const unsigned int*)(sb + (size_t)j2 * 64);
            unsigned int v3 = *(const unsigned int*)(sb + (size_t)j3 * 64);
            fmax2(t0, t1, v0);
            fmax2(t0, t1, v1);
            fmax2(t0, t1, v2);
            fmax2(t0, t1, v3);
        }
    }
    t0 = fmaxf(t0, __shfl_xor(t0, 32));
    t1 = fmaxf(t1, __shfl_xor(t1, 32));
    if (h == 0) {
        float x0 = x[wid * 3 + 0], xv1 = x[wid * 3 + 1], xv2 = x[wid * 3 + 2];
        int c1 = c0 + 1;
        float a0 = x0 * (W1[c0] - W1[192 + c0]) + xv1 * (W1[64 + c0] - W1[256 + c0]) +
                   xv2 * (W1[128 + c0] - W1[320 + c0]) + b1[c0];
        float a1 = x0 * (W1[c1] - W1[192 + c1]) + xv1 * (W1[64 + c1] - W1[256 + c1]) +
                   xv2 * (W1[128 + c1] - W1[320 + c1]) + b1[c1];
        *(unsigned int*)(x1 + (size_t)wid * 64 + c0) =
            pack2(fmaxf(a0 + t0, 0.f), fmaxf(a1 + t1, 0.f));
    }
}

// ---------------- fused edge-max + epilogue, C=128 (as rows [a(128)|s(128)]) ----------------
// 8-edge unroll: 8 outstanding uint loads per wave.

__global__ __launch_bounds__(256) void edge_fused128_kernel(
    const unsigned short* __restrict__ as, const int* __restrict__ rowstart,
    const int* __restrict__ csr, unsigned short* __restrict__ xout) {
    int wid = (blockIdx.x * 256 + threadIdx.x) >> 6;
    int lane = threadIdx.x & 63;
    if (wid >= NN) return;
    int e0 = __builtin_amdgcn_readfirstlane(rowstart[wid]);
    int e1 = __builtin_amdgcn_readfirstlane(rowstart[wid + 1]);
    float t0 = -INFINITY, t1 = -INFINITY;
    const unsigned short* sb = as + 128 + (size_t)lane * 2;
    int nedge = e1 - e0;
    for (int base = 0; base < nedge; base += 64) {
        int rem = nedge - base;
        int myj = csr[(lane < rem) ? (e0 + base + lane) : e0];
        int cnt = rem < 64 ? rem : 64;
        int cp = (cnt + 7) & ~7;
        for (int q = 0; q < cp; q += 8) {
            int j0 = __shfl(myj, q + 0), j1 = __shfl(myj, q + 1);
            int j2 = __shfl(myj, q + 2), j3 = __shfl(myj, q + 3);
            int j4 = __shfl(myj, q + 4), j5 = __shfl(myj, q + 5);
            int j6 = __shfl(myj, q + 6), j7 = __shfl(myj, q + 7);
            unsigned int v0 = *(const unsigned int*)(sb + (size_t)j0 * 256);
            unsigned int v1 = *(const unsigned int*)(sb + (size_t)j1 * 256);
            unsigned int v2 = *(const unsigned int*)(sb + (size_t)j2 * 256);
            unsigned int v3 = *(const unsigned int*)(sb + (size_t)j3 * 256);
            unsigned int v4 = *(const unsigned int*)(sb + (size_t)j4 * 256);
            unsigned int v5 = *(const unsigned int*)(sb + (size_t)j5 * 256);
            unsigned int v6 = *(const unsigned int*)(sb + (size_t)j6 * 256);
            unsigned int v7 = *(const unsigned int*)(sb + (size_t)j7 * 256);
            fmax2(t0, t1, v0); fmax2(t0, t1, v1);
            fmax2(t0, t1, v2); fmax2(t0, t1, v3);
            fmax2(t0, t1, v4); fmax2(t0, t1, v5);
            fmax2(t0, t1, v6); fmax2(t0, t1, v7);
        }
    }
    unsigned int av = *(const unsigned int*)(as + (size_t)wid * 256 + lane * 2);
    *(unsigned int*)(xout + (size_t)wid * 128 + lane * 2) = addrelu2(av, t0, t1);
}

// ---------------- fused edge-max + epilogue, C=512 (as rows [a(512)|s(512)]) ----------------
// 8-edge unroll: 8 outstanding uint4 (16B) loads per wave.

__global__ __launch_bounds__(256) void edge_fused512_kernel(
    const unsigned short* __restrict__ as, const int* __restrict__ rowstart,
    const int* __restrict__ csr, unsigned short* __restrict__ xout) {
    int wid = (blockIdx.x * 256 + threadIdx.x) >> 6;
    int lane = threadIdx.x & 63;
    if (wid >= NN) return;
    int e0 = __builtin_amdgcn_readfirstlane(rowstart[wid]);
    int e1 = __builtin_amdgcn_readfirstlane(rowstart[wid + 1]);
    float acc[8];
    #pragma unroll
    for (int v = 0; v < 8; ++v) acc[v] = -INFINITY;
    const unsigned short* sb = as + 512 + (size_t)lane * 8;
    int nedge = e1 - e0;
    for (int base = 0; base < nedge; base += 64) {
        int rem = nedge - base;
        int myj = csr[(lane < rem) ? (e0 + base + lane) : e0];
        int cnt = rem < 64 ? rem : 64;
        int cp = (cnt + 7) & ~7;
        for (int q = 0; q < cp; q += 8) {
            int j0 = __shfl(myj, q + 0), j1 = __shfl(myj, q + 1);
            int j2 = __shfl(myj, q + 2), j3 = __shfl(myj, q + 3);
            int j4 = __shfl(myj, q + 4), j5 = __shfl(myj, q + 5);
            int j6 = __shfl(myj, q + 6), j7 = __shfl(myj, q + 7);
            uint4 v0 = *(const uint4*)(sb + (size_t)j0 * 1024);
            uint4 v1 = *(const uint4*)(sb + (size_t)j1 * 1024);
            uint4 v2 = *(const uint4*)(sb + (size_t)j2 * 1024);
            uint4 v3 = *(const uint4*)(sb + (size_t)j3 * 1024);
            uint4 v4 = *(const uint4*)(sb + (size_t)j4 * 1024);
            uint4 v5 = *(const uint4*)(sb + (size_t)j5 * 1024);
            uint4 v6 = *(const uint4*)(sb + (size_t)j6 * 1024);
            uint4 v7 = *(const uint4*)(sb + (size_t)j7 * 1024);
            fmax2(acc[0], acc[1], v0.x); fmax2(acc[2], acc[3], v0.y);
            fmax2(acc[4], acc[5], v0.z); fmax2(acc[6], acc[7], v0.w);
            fmax2(acc[0], acc[1], v1.x); fmax2(acc[2], acc[3], v1.y);
            fmax2(acc[4], acc[5], v1.z); fmax2(acc[6], acc[7], v1.w);
            fmax2(acc[0], acc[1], v2.x); fmax2(acc[2], acc[3], v2.y);
            fmax2(acc[4], acc[5], v2.z); fmax2(acc[6], acc[7], v2.w);
            fmax2(acc[0], acc[1], v3.x); fmax2(acc[2], acc[3], v3.y);
            fmax2(acc[4], acc[5], v3.z); fmax2(acc[6], acc[7], v3.w);
            fmax2(acc[0], acc[1], v4.x); fmax2(acc[2], acc[3], v4.y);
            fmax2(acc[4], acc[5], v4.z); fmax2(acc[6], acc[7], v4.w);
            fmax2(acc[0], acc[1], v5.x); fmax2(acc[2], acc[3], v5.y);
            fmax2(acc[4], acc[5], v5.z); fmax2(acc[6], acc[7], v5.w);
            fmax2(acc[0], acc[1], v6.x); fmax2(acc[2], acc[3], v6.y);
            fmax2(acc[4], acc[5], v6.z); fmax2(acc[6], acc[7], v6.w);
            fmax2(acc[0], acc[1], v7.x); fmax2(acc[2], acc[3], v7.y);
            fmax2(acc[4], acc[5], v7.z); fmax2(acc[6], acc[7], v7.w);
        }
    }
    uint4 av = *(const uint4*)(as + (size_t)wid * 1024 + lane * 8);
    uint4 o;
    o.x = addrelu2(av.x, acc[0], acc[1]);
    o.y = addrelu2(av.y, acc[2], acc[3]);
    o.z = addrelu2(av.z, acc[4], acc[5]);
    o.w = addrelu2(av.w, acc[6], acc[7]);
    *(uint4*)(xout + (size_t)wid * 512 + lane * 8) = o;
}

// ---------------- MFMA GEMM: C_bf16 = epi(A_bf16[M,K] @ B), Bt = B^T bf16 [N][K] ----------------
// 128x128 block tile, 4 waves, each 64x64 via 4x4 mfma_f32_16x16x32_bf16.
// bias applied to cols < bias_n.

template<bool RELU>
__global__ __launch_bounds__(256) void mfma_gemm_kernel(
    const unsigned short* __restrict__ A, const unsigned short* __restrict__ Bt,
    const float* __restrict__ bias, int bias_n,
    unsigned short* __restrict__ C, int M, int N, int K) {
    __shared__ __align__(16) unsigned short Asl[128 * 40];  // [m][k], stride 40 (pad)
    __shared__ __align__(16) unsigned short Bsl[128 * 40];  // [n][k], stride 40
    int tid = threadIdx.x;
    int mbase = blockIdx.y * 128, nbase = blockIdx.x * 128;
    int wave = tid >> 6, lane = tid & 63;
    int wm = (wave >> 1) * 64, wn = (wave & 1) * 64;
    int quad = lane >> 4, l16 = lane & 15;
    f32x4 acc[4][4] = {};
    for (int kb = 0; kb < K; kb += 32) {
        #pragma unroll
        for (int h = 0; h < 2; ++h) {
            int c = tid + h * 256;           // 512 chunks of 16B
            int r = c >> 2, kk = (c & 3) * 8;
            uint4 va = make_uint4(0u, 0u, 0u, 0u);
            int gr = mbase + r;
            if (gr < M) va = *(const uint4*)&A[(size_t)gr * K + kb + kk];
            *(uint4*)&Asl[r * 40 + kk] = va;
            uint4 vb = *(const uint4*)&Bt[(size_t)(nbase + r) * K + kb + kk];
            *(uint4*)&Bsl[r * 40 + kk] = vb;
        }
        __syncthreads();
        bf16x8 af[4], bfr[4];
        #pragma unroll
        for (int tt = 0; tt < 4; ++tt) {
            af[tt]  = *(const bf16x8*)&Asl[(wm + tt * 16 + l16) * 40 + quad * 8];
            bfr[tt] = *(const bf16x8*)&Bsl[(wn + tt * 16 + l16) * 40 + quad * 8];
        }
        #pragma unroll
        for (int mt = 0; mt < 4; ++mt)
            #pragma unroll
            for (int nt = 0; nt < 4; ++nt)
                acc[mt][nt] = __builtin_amdgcn_mfma_f32_16x16x32_bf16(
                    af[mt], bfr[nt], acc[mt][nt], 0, 0, 0);
        __syncthreads();
    }
    #pragma unroll
    for (int mt = 0; mt < 4; ++mt) {
        #pragma unroll
        for (int r = 0; r < 4; ++r) {
            int row = mbase + wm + mt * 16 + quad * 4 + r;
            if (row >= M) continue;
            #pragma unroll
            for (int nt = 0; nt < 4; ++nt) {
                int col = nbase + wn + nt * 16 + l16;
                float v = acc[mt][nt][r];
                if (col < bias_n) v += bias[col];
                if (RELU) v = fmaxf(v, 0.f);
                C[(size_t)row * N + col] = f2bf(v);
            }
        }
    }
}

// ---------------- final: out = x + h4 @ W5 + b5 (one wave per node) ----------------

__global__ void final_kernel(const unsigned short* __restrict__ h4,
                             const float* __restrict__ W5, const float* __restrict__ b5,
                             const float* __restrict__ x, float* __restrict__ out) {
    int gt = blockIdx.x * blockDim.x + threadIdx.x;
    int node = gt >> 6;
    int lane = gt & 63;
    if (node >= NN) return;
    ushort4 hv = ((const ushort4*)(h4 + (size_t)node * 256))[lane];
    float hj[4] = {bf2f_raw(hv.x), bf2f_raw(hv.y), bf2f_raw(hv.z), bf2f_raw(hv.w)};
    float acc0 = 0.f, acc1 = 0.f, acc2 = 0.f;
    #pragma unroll
    for (int j = 0; j < 4; ++j) {
        int k = lane * 4 + j;
        acc0 += hj[j] * W5[k * 3 + 0];
        acc1 += hj[j] * W5[k * 3 + 1];
        acc2 += hj[j] * W5[k * 3 + 2];
    }
    #pragma unroll
    for (int off = 32; off; off >>= 1) {
        acc0 += __shfl_down(acc0, off);
        acc1 += __shfl_down(acc1, off);
        acc2 += __shfl_down(acc2, off);
    }
    if (lane == 0) {
        out[node * 3 + 0] = x[node * 3 + 0] + acc0 + b5[0];
        out[node * 3 + 1] = x[node * 3 + 1] + acc1 + b5[1];
        out[node * 3 + 2] = x[node * 3 + 2] + acc2 + b5[2];
    }
}

__global__ void fallback_copy_kernel(const float* __restrict__ x, float* __restrict__ out) {
    int t = blockIdx.x * blockDim.x + threadIdx.x;
    if (t < NN * 3) out[t] = x[t];
}

// ---------------- launcher ----------------

extern "C" void kernel_launch(void* const* d_in, const int* in_sizes, int n_in,
                              void* d_out, int out_size, void* d_ws, size_t ws_size,
                              hipStream_t stream) {
    const float* x  = (const float*)d_in[0];
    const int*   ei = (const int*)d_in[1];
    const float* W1 = (const float*)d_in[2];
    const float* b1 = (const float*)d_in[3];
    const float* W2 = (const float*)d_in[4];
    const float* b2 = (const float*)d_in[5];
    const float* W3 = (const float*)d_in[6];
    const float* b3 = (const float*)d_in[7];
    const float* W4 = (const float*)d_in[8];
    const float* b4 = (const float*)d_in[9];
    const float* W5 = (const float*)d_in[10];
    const float* b5 = (const float*)d_in[11];
    float* out = (float*)d_out;

    char* p = (char*)d_ws;
    auto alloc = [&](size_t bytes) -> void* {
        void* r = (void*)p;
        p += (bytes + 255) & ~(size_t)255;
        return r;
    };
    int* deg      = (int*)alloc((size_t)NN * 4);
    int* rowstart = (int*)alloc((size_t)(NN + 1) * 4);
    int* cursor   = (int*)alloc((size_t)NN * 4);
    int* csr      = (int*)alloc((size_t)NE * 4);
    unsigned short* Bt2 = (unsigned short*)alloc(256 * 64 * 2);    // [Wtb2^T ; Wb2^T]
    unsigned short* Bt3 = (unsigned short*)alloc(1024 * 128 * 2);  // [Wtb3^T ; Wb3^T]
    unsigned short* W4t = (unsigned short*)alloc(256 * 512 * 2);
    unsigned short* x1 = (unsigned short*)alloc((size_t)NN * 64 * 2);
    unsigned short* x2 = (unsigned short*)alloc((size_t)NN * 128 * 2);
    unsigned short* x3 = (unsigned short*)alloc((size_t)NN * 512 * 2);
    unsigned short* as_slab = (unsigned short*)alloc((size_t)NN * 1024 * 2);  // s1/as2/as3/h4
    size_t need = (size_t)(p - (char*)d_ws);
    if (ws_size < need) {
        fallback_copy_kernel<<<(NN * 3 + 255) / 256, 256, 0, stream>>>(x, out);
        return;
    }
    unsigned short* s1 = as_slab;
    unsigned short* h4 = as_slab;

    const int* src = ei;        // edge_index[0]
    const int* dst = ei + NE;   // edge_index[1]

    // CSR by dst (graph static across all 3 convs)
    hipMemsetAsync(deg, 0, (size_t)NN * 4, stream);
    hipMemsetAsync(cursor, 0, (size_t)NN * 4, stream);
    hist_kernel<<<(NE + 255) / 256, 256, 0, stream>>>(dst, deg);
    scan_kernel<<<1, 1024, 0, stream>>>(deg, rowstart);
    scatter_kernel<<<(NE + 255) / 256, 256, 0, stream>>>(src, dst, rowstart, cursor, csr);

    // bf16 transposed weights (combined [Wtb;Wb] for conv GEMMs)
    prep_split_t_kernel<64, 128><<<32, 256, 0, stream>>>(W2, Bt2, Bt2 + 128 * 64);
    prep_split_t_kernel<128, 512><<<256, 256, 0, stream>>>(W3, Bt3, Bt3 + 512 * 128);
    prep_t_kernel<512, 256><<<512, 256, 0, stream>>>(W4, W4t);

    // conv1: s1 = x@Wb1 ; x1 = relu(a1 + max_j s1[j])  (a1 inline)
    conv1_s_kernel<<<NN * 64 / 256, 256, 0, stream>>>(x, W1, s1);
    edge_fused_conv1_kernel<<<12500, 256, 0, stream>>>(s1, rowstart, csr, x, W1, b1, x1);

    // conv2: as2 = x1 @ [Wtb2|Wb2] (+b2 on a-half); x2 = relu(a2 + max s2)
    mfma_gemm_kernel<false><<<dim3(2, 391), 256, 0, stream>>>(
        x1, Bt2, b2, 128, as_slab, NN, 256, 64);
    edge_fused128_kernel<<<12500, 256, 0, stream>>>(as_slab, rowstart, csr, x2);

    // conv3: as3 = x2 @ [Wtb3|Wb3] (+b3 on a-half); x3 = relu(a3 + max s3)
    mfma_gemm_kernel<false><<<dim3(8, 391), 256, 0, stream>>>(
        x2, Bt3, b3, 512, as_slab, NN, 1024, 128);
    edge_fused512_kernel<<<12500, 256, 0, stream>>>(as_slab, rowstart, csr, x3);

    // h4 = relu(x3 @ W4 + b4)
    mfma_gemm_kernel<true><<<dim3(2, 391), 256, 0, stream>>>(
        x3, W4t, b4, 256, h4, NN, 256, 512);

    // out = x + h4 @ W5 + b5
    final_kernel<<<NN / 4, 256, 0, stream>>>(h4, W5, b5, x, out);
}

// Round 6
// 631.929 us; speedup vs baseline: 1.0038x; 1.0038x over previous
//
#include <hip/hip_runtime.h>

static constexpr int NN = 50000;
static constexpr int NE = 1000000;

typedef short bf16x8 __attribute__((ext_vector_type(8)));
typedef float f32x4 __attribute__((ext_vector_type(4)));

__device__ inline float bf2f_raw(unsigned short u) {
    return __uint_as_float(((unsigned int)u) << 16);
}
__device__ inline unsigned short f2bf(float f) {
    unsigned int u = __float_as_uint(f);
    u += 0x7fffu + ((u >> 16) & 1u);
    return (unsigned short)(u >> 16);
}
__device__ inline void fmax2(float& a0, float& a1, unsigned int v) {
    a0 = fmaxf(a0, bf2f_raw((unsigned short)(v & 0xffffu)));
    a1 = fmaxf(a1, bf2f_raw((unsigned short)(v >> 16)));
}
__device__ inline unsigned int pack2(float f0, float f1) {
    return (unsigned int)f2bf(f0) | ((unsigned int)f2bf(f1) << 16);
}
__device__ inline unsigned int addrelu2(unsigned int a, float t0, float t1) {
    float f0 = fmaxf(bf2f_raw((unsigned short)(a & 0xffffu)) + t0, 0.f);
    float f1 = fmaxf(bf2f_raw((unsigned short)(a >> 16)) + t1, 0.f);
    return pack2(f0, f1);
}

// ---------------- out init: out = x + b5 ----------------

__global__ void init_out_kernel(const float* __restrict__ x, const float* __restrict__ b5,
                                float* __restrict__ out) {
    int t = blockIdx.x * blockDim.x + threadIdx.x;
    if (t < NN * 3) out[t] = x[t] + b5[t % 3];
}

// ---------------- CSR build ----------------

__global__ void hist_kernel(const int* __restrict__ dst, int* __restrict__ deg) {
    int e = blockIdx.x * blockDim.x + threadIdx.x;
    if (e < NE) atomicAdd(&deg[dst[e]], 1);
}

__global__ __launch_bounds__(1024) void scan_kernel(const int* __restrict__ deg,
                                                    int* __restrict__ rowstart,
                                                    int* __restrict__ cursor) {
    __shared__ int wave_sums[16];
    __shared__ int carry_s;
    int tid = threadIdx.x;
    int lane = tid & 63;
    int wave = tid >> 6;
    for (int i = tid; i < NN; i += 1024) cursor[i] = 0;  // replaces a memset dispatch
    if (tid == 0) carry_s = 0;
    __syncthreads();
    for (int base = 0; base < NN; base += 1024) {
        int idx = base + tid;
        int v = (idx < NN) ? deg[idx] : 0;
        int x = v;
        #pragma unroll
        for (int off = 1; off < 64; off <<= 1) {
            int y = __shfl_up(x, off);
            if (lane >= off) x += y;
        }
        if (lane == 63) wave_sums[wave] = x;
        __syncthreads();
        if (wave == 0 && lane < 16) {
            int s = wave_sums[lane];
            #pragma unroll
            for (int off = 1; off < 16; off <<= 1) {
                int y = __shfl_up(s, off);
                if (lane >= off) s += y;
            }
            wave_sums[lane] = s;
        }
        __syncthreads();
        int wave_off = wave ? wave_sums[wave - 1] : 0;
        int chunk_total = wave_sums[15];
        int carry = carry_s;
        if (idx < NN) rowstart[idx] = carry + wave_off + x - v;  // exclusive scan
        __syncthreads();
        if (tid == 0) carry_s = carry + chunk_total;
        __syncthreads();
    }
    if (tid == 0) rowstart[NN] = carry_s;
}

__global__ void scatter_kernel(const int* __restrict__ src, const int* __restrict__ dst,
                               const int* __restrict__ rowstart, int* __restrict__ cursor,
                               int* __restrict__ csr) {
    int e = blockIdx.x * blockDim.x + threadIdx.x;
    if (e < NE) {
        int d = dst[e];
        int pos = atomicAdd(&cursor[d], 1);
        csr[rowstart[d] + pos] = src[e];
    }
}

// ---------------- all weight prep in one dispatch ----------------
// range 0: W2 split  (64x128)   -> Bt2 = [Wtb2^T ; Wb2^T]   (256x64)
// range 1: W3 split  (128x512)  -> Bt3 = [Wtb3^T ; Wb3^T]   (1024x128)
// range 2: W4 transpose (512x256) -> W4t (256x512)

__global__ void prep_all_kernel(const float* __restrict__ W2, const float* __restrict__ W3,
                                const float* __restrict__ W4,
                                unsigned short* __restrict__ Bt2,
                                unsigned short* __restrict__ Bt3,
                                unsigned short* __restrict__ W4t) {
    int t = blockIdx.x * blockDim.x + threadIdx.x;
    if (t < 8192) {  // 64*128
        int k = t / 128, c = t % 128;
        float wt = W2[k * 128 + c];
        float wb = W2[(64 + k) * 128 + c];
        Bt2[c * 64 + k] = f2bf(wt - wb);
        Bt2[(128 + c) * 64 + k] = f2bf(wb);
    } else if (t < 8192 + 65536) {  // 128*512
        int u = t - 8192;
        int k = u / 512, c = u % 512;
        float wt = W3[k * 512 + c];
        float wb = W3[(128 + k) * 512 + c];
        Bt3[c * 128 + k] = f2bf(wt - wb);
        Bt3[(512 + c) * 128 + k] = f2bf(wb);
    } else if (t < 8192 + 65536 + 131072) {  // 512*256
        int u = t - 8192 - 65536;
        int k = u / 256, n = u % 256;
        W4t[n * 512 + k] = f2bf(W4[k * 256 + n]);
    }
}

// ---------------- conv1 s = x @ Wb1 (K=3, elementwise) ----------------

__global__ void conv1_s_kernel(const float* __restrict__ x, const float* __restrict__ W1,
                               unsigned short* __restrict__ s) {
    int t = blockIdx.x * blockDim.x + threadIdx.x;
    int i = t >> 6, c = t & 63;
    if (i >= NN) return;
    float v = x[i * 3 + 0] * W1[3 * 64 + c] + x[i * 3 + 1] * W1[4 * 64 + c] +
              x[i * 3 + 2] * W1[5 * 64 + c];
    s[t] = f2bf(v);
}

// ---------------- conv1 fused edge-max + epilogue (C=64) ----------------

__global__ __launch_bounds__(256) void edge_fused_conv1_kernel(
    const unsigned short* __restrict__ s1, const int* __restrict__ rowstart,
    const int* __restrict__ csr, const float* __restrict__ x,
    const float* __restrict__ W1, const float* __restrict__ b1,
    unsigned short* __restrict__ x1) {
    int wid = (blockIdx.x * 256 + threadIdx.x) >> 6;
    int lane = threadIdx.x & 63;
    if (wid >= NN) return;
    int e0 = __builtin_amdgcn_readfirstlane(rowstart[wid]);
    int e1 = __builtin_amdgcn_readfirstlane(rowstart[wid + 1]);
    int h = lane >> 5, c0 = (lane & 31) * 2;
    float t0 = -INFINITY, t1 = -INFINITY;
    const unsigned short* sb = s1 + c0;
    int nedge = e1 - e0;
    for (int base = 0; base < nedge; base += 64) {
        int rem = nedge - base;
        int myj = csr[(lane < rem) ? (e0 + base + lane) : e0];
        int cnt = rem < 64 ? rem : 64;
        int cp = (cnt + 7) & ~7;
        for (int q = 0; q < cp; q += 8) {
            int j0 = __shfl(myj, q + 0 + h);
            int j1 = __shfl(myj, q + 2 + h);
            int j2 = __shfl(myj, q + 4 + h);
            int j3 = __shfl(myj, q + 6 + h);
            unsigned int v0 = *(const unsigned int*)(sb + (size_t)j0 * 64);
            unsigned int v1 = *(const unsigned int*)(sb + (size_t)j1 * 64);
            unsigned int v2 = *(const unsigned int*)(sb + (size_t)j2 * 64);
            unsigned int v3 = *(const unsigned int*)(sb + (size_t)j3 * 64);
            fmax2(t0, t1, v0);
            fmax2(t0, t1, v1);
            fmax2(t0, t1, v2);
            fmax2(t0, t1, v3);
        }
    }
    t0 = fmaxf(t0, __shfl_xor(t0, 32));
    t1 = fmaxf(t1, __shfl_xor(t1, 32));
    if (h == 0) {
        float x0 = x[wid * 3 + 0], xv1 = x[wid * 3 + 1], xv2 = x[wid * 3 + 2];
        int c1 = c0 + 1;
        float a0 = x0 * (W1[c0] - W1[192 + c0]) + xv1 * (W1[64 + c0] - W1[256 + c0]) +
                   xv2 * (W1[128 + c0] - W1[320 + c0]) + b1[c0];
        float a1 = x0 * (W1[c1] - W1[192 + c1]) + xv1 * (W1[64 + c1] - W1[256 + c1]) +
                   xv2 * (W1[128 + c1] - W1[320 + c1]) + b1[c1];
        *(unsigned int*)(x1 + (size_t)wid * 64 + c0) =
            pack2(fmaxf(a0 + t0, 0.f), fmaxf(a1 + t1, 0.f));
    }
}

// ---------------- fused edge-max + epilogue, C=128 (as rows [a(128)|s(128)]) ----------------

__global__ __launch_bounds__(256) void edge_fused128_kernel(
    const unsigned short* __restrict__ as, const int* __restrict__ rowstart,
    const int* __restrict__ csr, unsigned short* __restrict__ xout) {
    int wid = (blockIdx.x * 256 + threadIdx.x) >> 6;
    int lane = threadIdx.x & 63;
    if (wid >= NN) return;
    int e0 = __builtin_amdgcn_readfirstlane(rowstart[wid]);
    int e1 = __builtin_amdgcn_readfirstlane(rowstart[wid + 1]);
    float t0 = -INFINITY, t1 = -INFINITY;
    const unsigned short* sb = as + 128 + (size_t)lane * 2;
    int nedge = e1 - e0;
    for (int base = 0; base < nedge; base += 64) {
        int rem = nedge - base;
        int myj = csr[(lane < rem) ? (e0 + base + lane) : e0];
        int cnt = rem < 64 ? rem : 64;
        int cp = (cnt + 7) & ~7;
        for (int q = 0; q < cp; q += 8) {
            int j0 = __shfl(myj, q + 0), j1 = __shfl(myj, q + 1);
            int j2 = __shfl(myj, q + 2), j3 = __shfl(myj, q + 3);
            int j4 = __shfl(myj, q + 4), j5 = __shfl(myj, q + 5);
            int j6 = __shfl(myj, q + 6), j7 = __shfl(myj, q + 7);
            unsigned int v0 = *(const unsigned int*)(sb + (size_t)j0 * 256);
            unsigned int v1 = *(const unsigned int*)(sb + (size_t)j1 * 256);
            unsigned int v2 = *(const unsigned int*)(sb + (size_t)j2 * 256);
            unsigned int v3 = *(const unsigned int*)(sb + (size_t)j3 * 256);
            unsigned int v4 = *(const unsigned int*)(sb + (size_t)j4 * 256);
            unsigned int v5 = *(const unsigned int*)(sb + (size_t)j5 * 256);
            unsigned int v6 = *(const unsigned int*)(sb + (size_t)j6 * 256);
            unsigned int v7 = *(const unsigned int*)(sb + (size_t)j7 * 256);
            fmax2(t0, t1, v0); fmax2(t0, t1, v1);
            fmax2(t0, t1, v2); fmax2(t0, t1, v3);
            fmax2(t0, t1, v4); fmax2(t0, t1, v5);
            fmax2(t0, t1, v6); fmax2(t0, t1, v7);
        }
    }
    unsigned int av = *(const unsigned int*)(as + (size_t)wid * 256 + lane * 2);
    *(unsigned int*)(xout + (size_t)wid * 128 + lane * 2) = addrelu2(av, t0, t1);
}

// ---------------- fused edge-max + epilogue, C=512 (as rows [a(512)|s(512)]) ----------------

__global__ __launch_bounds__(256) void edge_fused512_kernel(
    const unsigned short* __restrict__ as, const int* __restrict__ rowstart,
    const int* __restrict__ csr, unsigned short* __restrict__ xout) {
    int wid = (blockIdx.x * 256 + threadIdx.x) >> 6;
    int lane = threadIdx.x & 63;
    if (wid >= NN) return;
    int e0 = __builtin_amdgcn_readfirstlane(rowstart[wid]);
    int e1 = __builtin_amdgcn_readfirstlane(rowstart[wid + 1]);
    float acc[8];
    #pragma unroll
    for (int v = 0; v < 8; ++v) acc[v] = -INFINITY;
    const unsigned short* sb = as + 512 + (size_t)lane * 8;
    int nedge = e1 - e0;
    for (int base = 0; base < nedge; base += 64) {
        int rem = nedge - base;
        int myj = csr[(lane < rem) ? (e0 + base + lane) : e0];
        int cnt = rem < 64 ? rem : 64;
        int cp = (cnt + 3) & ~3;
        for (int q = 0; q < cp; q += 4) {
            int j0 = __shfl(myj, q + 0), j1 = __shfl(myj, q + 1);
            int j2 = __shfl(myj, q + 2), j3 = __shfl(myj, q + 3);
            uint4 v0 = *(const uint4*)(sb + (size_t)j0 * 1024);
            uint4 v1 = *(const uint4*)(sb + (size_t)j1 * 1024);
            uint4 v2 = *(const uint4*)(sb + (size_t)j2 * 1024);
            uint4 v3 = *(const uint4*)(sb + (size_t)j3 * 1024);
            fmax2(acc[0], acc[1], v0.x); fmax2(acc[2], acc[3], v0.y);
            fmax2(acc[4], acc[5], v0.z); fmax2(acc[6], acc[7], v0.w);
            fmax2(acc[0], acc[1], v1.x); fmax2(acc[2], acc[3], v1.y);
            fmax2(acc[4], acc[5], v1.z); fmax2(acc[6], acc[7], v1.w);
            fmax2(acc[0], acc[1], v2.x); fmax2(acc[2], acc[3], v2.y);
            fmax2(acc[4], acc[5], v2.z); fmax2(acc[6], acc[7], v2.w);
            fmax2(acc[0], acc[1], v3.x); fmax2(acc[2], acc[3], v3.y);
            fmax2(acc[4], acc[5], v3.z); fmax2(acc[6], acc[7], v3.w);
        }
    }
    uint4 av = *(const uint4*)(as + (size_t)wid * 1024 + lane * 8);
    uint4 o;
    o.x = addrelu2(av.x, acc[0], acc[1]);
    o.y = addrelu2(av.y, acc[2], acc[3]);
    o.z = addrelu2(av.z, acc[4], acc[5]);
    o.w = addrelu2(av.w, acc[6], acc[7]);
    *(uint4*)(xout + (size_t)wid * 512 + lane * 8) = o;
}

// ---------------- MFMA GEMM: C_bf16 = A_bf16[M,K] @ B (+bias on cols < bias_n) ----------------

__global__ __launch_bounds__(256) void mfma_gemm_kernel(
    const unsigned short* __restrict__ A, const unsigned short* __restrict__ Bt,
    const float* __restrict__ bias, int bias_n,
    unsigned short* __restrict__ C, int M, int N, int K) {
    __shared__ __align__(16) unsigned short Asl[128 * 40];
    __shared__ __align__(16) unsigned short Bsl[128 * 40];
    int tid = threadIdx.x;
    int mbase = blockIdx.y * 128, nbase = blockIdx.x * 128;
    int wave = tid >> 6, lane = tid & 63;
    int wm = (wave >> 1) * 64, wn = (wave & 1) * 64;
    int quad = lane >> 4, l16 = lane & 15;
    f32x4 acc[4][4] = {};
    for (int kb = 0; kb < K; kb += 32) {
        #pragma unroll
        for (int h = 0; h < 2; ++h) {
            int c = tid + h * 256;
            int r = c >> 2, kk = (c & 3) * 8;
            uint4 va = make_uint4(0u, 0u, 0u, 0u);
            int gr = mbase + r;
            if (gr < M) va = *(const uint4*)&A[(size_t)gr * K + kb + kk];
            *(uint4*)&Asl[r * 40 + kk] = va;
            uint4 vb = *(const uint4*)&Bt[(size_t)(nbase + r) * K + kb + kk];
            *(uint4*)&Bsl[r * 40 + kk] = vb;
        }
        __syncthreads();
        bf16x8 af[4], bfr[4];
        #pragma unroll
        for (int tt = 0; tt < 4; ++tt) {
            af[tt]  = *(const bf16x8*)&Asl[(wm + tt * 16 + l16) * 40 + quad * 8];
            bfr[tt] = *(const bf16x8*)&Bsl[(wn + tt * 16 + l16) * 40 + quad * 8];
        }
        #pragma unroll
        for (int mt = 0; mt < 4; ++mt)
            #pragma unroll
            for (int nt = 0; nt < 4; ++nt)
                acc[mt][nt] = __builtin_amdgcn_mfma_f32_16x16x32_bf16(
                    af[mt], bfr[nt], acc[mt][nt], 0, 0, 0);
        __syncthreads();
    }
    #pragma unroll
    for (int mt = 0; mt < 4; ++mt) {
        #pragma unroll
        for (int r = 0; r < 4; ++r) {
            int row = mbase + wm + mt * 16 + quad * 4 + r;
            if (row >= M) continue;
            #pragma unroll
            for (int nt = 0; nt < 4; ++nt) {
                int col = nbase + wn + nt * 16 + l16;
                float v = acc[mt][nt][r];
                if (col < bias_n) v += bias[col];
                C[(size_t)row * N + col] = f2bf(v);
            }
        }
    }
}

// ---------------- fused last stage: out += relu(x3@W4 + b4) @ W5 ----------------
// Same GEMM core (M=NN, N=256, K=512, Bt=W4t). No C store; epilogue contracts the
// 128x128 h-tile with W5[col][3] via 16-lane shuffle reduce, atomicAdd into out.

__global__ __launch_bounds__(256) void mfma_gemm_w5_kernel(
    const unsigned short* __restrict__ A, const unsigned short* __restrict__ Bt,
    const float* __restrict__ b4, const float* __restrict__ W5,
    float* __restrict__ out, int M, int K) {
    __shared__ __align__(16) unsigned short Asl[128 * 40];
    __shared__ __align__(16) unsigned short Bsl[128 * 40];
    int tid = threadIdx.x;
    int mbase = blockIdx.y * 128, nbase = blockIdx.x * 128;
    int wave = tid >> 6, lane = tid & 63;
    int wm = (wave >> 1) * 64, wn = (wave & 1) * 64;
    int quad = lane >> 4, l16 = lane & 15;
    f32x4 acc[4][4] = {};
    for (int kb = 0; kb < K; kb += 32) {
        #pragma unroll
        for (int h = 0; h < 2; ++h) {
            int c = tid + h * 256;
            int r = c >> 2, kk = (c & 3) * 8;
            uint4 va = make_uint4(0u, 0u, 0u, 0u);
            int gr = mbase + r;
            if (gr < M) va = *(const uint4*)&A[(size_t)gr * K + kb + kk];
            *(uint4*)&Asl[r * 40 + kk] = va;
            uint4 vb = *(const uint4*)&Bt[(size_t)(nbase + r) * K + kb + kk];
            *(uint4*)&Bsl[r * 40 + kk] = vb;
        }
        __syncthreads();
        bf16x8 af[4], bfr[4];
        #pragma unroll
        for (int tt = 0; tt < 4; ++tt) {
            af[tt]  = *(const bf16x8*)&Asl[(wm + tt * 16 + l16) * 40 + quad * 8];
            bfr[tt] = *(const bf16x8*)&Bsl[(wn + tt * 16 + l16) * 40 + quad * 8];
        }
        #pragma unroll
        for (int mt = 0; mt < 4; ++mt)
            #pragma unroll
            for (int nt = 0; nt < 4; ++nt)
                acc[mt][nt] = __builtin_amdgcn_mfma_f32_16x16x32_bf16(
                    af[mt], bfr[nt], acc[mt][nt], 0, 0, 0);
        __syncthreads();
    }
    // per-lane column constants
    float w5r[4][3], b4v[4];
    #pragma unroll
    for (int nt = 0; nt < 4; ++nt) {
        int col = nbase + wn + nt * 16 + l16;
        b4v[nt] = b4[col];
        w5r[nt][0] = W5[col * 3 + 0];
        w5r[nt][1] = W5[col * 3 + 1];
        w5r[nt][2] = W5[col * 3 + 2];
    }
    #pragma unroll
    for (int mt = 0; mt < 4; ++mt) {
        #pragma unroll
        for (int r = 0; r < 4; ++r) {
            int row = mbase + wm + mt * 16 + quad * 4 + r;
            float p0 = 0.f, p1 = 0.f, p2 = 0.f;
            #pragma unroll
            for (int nt = 0; nt < 4; ++nt) {
                float h = fmaxf(acc[mt][nt][r] + b4v[nt], 0.f);
                p0 += h * w5r[nt][0];
                p1 += h * w5r[nt][1];
                p2 += h * w5r[nt][2];
            }
            #pragma unroll
            for (int m = 8; m; m >>= 1) {  // reduce over l16 (stays within quad)
                p0 += __shfl_xor(p0, m);
                p1 += __shfl_xor(p1, m);
                p2 += __shfl_xor(p2, m);
            }
            if (l16 == 0 && row < M) {
                atomicAdd(&out[row * 3 + 0], p0);
                atomicAdd(&out[row * 3 + 1], p1);
                atomicAdd(&out[row * 3 + 2], p2);
            }
        }
    }
}

__global__ void fallback_copy_kernel(const float* __restrict__ x, float* __restrict__ out) {
    int t = blockIdx.x * blockDim.x + threadIdx.x;
    if (t < NN * 3) out[t] = x[t];
}

// ---------------- launcher ----------------

extern "C" void kernel_launch(void* const* d_in, const int* in_sizes, int n_in,
                              void* d_out, int out_size, void* d_ws, size_t ws_size,
                              hipStream_t stream) {
    const float* x  = (const float*)d_in[0];
    const int*   ei = (const int*)d_in[1];
    const float* W1 = (const float*)d_in[2];
    const float* b1 = (const float*)d_in[3];
    const float* W2 = (const float*)d_in[4];
    const float* b2 = (const float*)d_in[5];
    const float* W3 = (const float*)d_in[6];
    const float* b3 = (const float*)d_in[7];
    const float* W4 = (const float*)d_in[8];
    const float* b4 = (const float*)d_in[9];
    const float* W5 = (const float*)d_in[10];
    const float* b5 = (const float*)d_in[11];
    float* out = (float*)d_out;

    char* p = (char*)d_ws;
    auto alloc = [&](size_t bytes) -> void* {
        void* r = (void*)p;
        p += (bytes + 255) & ~(size_t)255;
        return r;
    };
    int* deg      = (int*)alloc((size_t)NN * 4);
    int* rowstart = (int*)alloc((size_t)(NN + 1) * 4);
    int* cursor   = (int*)alloc((size_t)NN * 4);
    int* csr      = (int*)alloc((size_t)NE * 4);
    unsigned short* Bt2 = (unsigned short*)alloc(256 * 64 * 2);
    unsigned short* Bt3 = (unsigned short*)alloc(1024 * 128 * 2);
    unsigned short* W4t = (unsigned short*)alloc(256 * 512 * 2);
    unsigned short* x1 = (unsigned short*)alloc((size_t)NN * 64 * 2);
    unsigned short* x2 = (unsigned short*)alloc((size_t)NN * 128 * 2);
    unsigned short* x3 = (unsigned short*)alloc((size_t)NN * 512 * 2);
    unsigned short* as_slab = (unsigned short*)alloc((size_t)NN * 1024 * 2);  // s1/as2/as3
    size_t need = (size_t)(p - (char*)d_ws);
    if (ws_size < need) {
        fallback_copy_kernel<<<(NN * 3 + 255) / 256, 256, 0, stream>>>(x, out);
        return;
    }
    unsigned short* s1 = as_slab;

    const int* src = ei;        // edge_index[0]
    const int* dst = ei + NE;   // edge_index[1]

    // out = x + b5 (atomics accumulate the final GEMM contribution later)
    init_out_kernel<<<(NN * 3 + 255) / 256, 256, 0, stream>>>(x, b5, out);

    // CSR by dst (graph static across all 3 convs)
    hipMemsetAsync(deg, 0, (size_t)NN * 4, stream);
    hist_kernel<<<(NE + 255) / 256, 256, 0, stream>>>(dst, deg);
    scan_kernel<<<1, 1024, 0, stream>>>(deg, rowstart, cursor);
    scatter_kernel<<<(NE + 255) / 256, 256, 0, stream>>>(src, dst, rowstart, cursor, csr);

    // all weight prep in one dispatch
    prep_all_kernel<<<800, 256, 0, stream>>>(W2, W3, W4, Bt2, Bt3, W4t);

    // conv1: s1 = x@Wb1 ; x1 = relu(a1 + max_j s1[j])  (a1 inline)
    conv1_s_kernel<<<NN * 64 / 256, 256, 0, stream>>>(x, W1, s1);
    edge_fused_conv1_kernel<<<12500, 256, 0, stream>>>(s1, rowstart, csr, x, W1, b1, x1);

    // conv2: as2 = x1 @ [Wtb2|Wb2] (+b2 on a-half); x2 = relu(a2 + max s2)
    mfma_gemm_kernel<<<dim3(2, 391), 256, 0, stream>>>(
        x1, Bt2, b2, 128, as_slab, NN, 256, 64);
    edge_fused128_kernel<<<12500, 256, 0, stream>>>(as_slab, rowstart, csr, x2);

    // conv3: as3 = x2 @ [Wtb3|Wb3] (+b3 on a-half); x3 = relu(a3 + max s3)
    mfma_gemm_kernel<<<dim3(8, 391), 256, 0, stream>>>(
        x2, Bt3, b3, 512, as_slab, NN, 1024, 128);
    edge_fused512_kernel<<<12500, 256, 0, stream>>>(as_slab, rowstart, csr, x3);

    // out += relu(x3@W4 + b4) @ W5   (fused, no h4 materialization)
    mfma_gemm_w5_kernel<<<dim3(2, 391), 256, 0, stream>>>(
        x3, W4t, b4, W5, out, NN, 512);
}